// Round 5
// baseline (277.120 us; speedup 1.0000x reference)
//
#include <hip/hip_runtime.h>

// HiearchicalFFTShiftModel: closed-form spectrum with EXACT emulation of the
// reference's complex64 phase quantization, + fused chain+FFT pass and two
// transpose-FFT passes over 2^24 complex points (c2r packing).
//
// Round-5 change vs 271us: B/C were stuck at ~100us each (2.8 TB/s effective)
// across compute/LDS/prefetch changes -> DRAM granularity bound (128-B chunks
// per stride point). Rebuilt B/C with 32x256 tiles (512 thr, 64 KiB LDS):
//   B: reads 256-B chunks @2KB stride, writes L2 = t2*65536+t3*256+k1 in
//      256-B chunks. 1 barrier.
//   C: reads L2 as a fully CONTIGUOUS 64-KB slab, writes output in 256-B
//      chunks. 2 barriers.
// LDS uses a per-row column rotation (col -> (col+row)&255) instead of
// padding: exactly 64 KiB static, every b64 access at the 4-lane/bank-pair
// floor (verified per pattern). Per-element float sequences unchanged ->
// absmax must stay exactly 1.525879e-05. A and build_q untouched.

constexpr float TWOPI_F = 6.28318530717958647692f;
constexpr unsigned M24 = 1u << 24;

__device__ __forceinline__ void phase_sincos(float th, float* sn, float* cs) {
    double d = (double)th * 0.15915494309189533577;  // 1/(2*pi)
    d -= rint(d);                                    // frac in [-0.5, 0.5]
    float ang = (float)(d * 6.2831853071795864769);  // [-pi, pi]
    __sincosf(ang, sn, cs);
}

__device__ __forceinline__ float2 cmul(float2 a, float2 f) {
    return make_float2(a.x * f.x - a.y * f.y, a.x * f.y + a.y * f.x);
}
__device__ __forceinline__ float2 caddf(float2 a, float2 b) { return make_float2(a.x + b.x, a.y + b.y); }
__device__ __forceinline__ float2 csubf(float2 a, float2 b) { return make_float2(a.x - b.x, a.y - b.y); }
__device__ __forceinline__ float2 cmulw(float2 a, float c, float s) {
    return make_float2(a.x * c - a.y * s, a.x * s + a.y * c);
}

// chunked bijective XCD swizzle (nblocks divisible by 8)
__device__ __forceinline__ int xcd_swizzle(int b, int nblocks) {
    int chunk = nblocks >> 3;
    return (b & 7) * chunk + (b >> 3);
}

// rotated LDS addressing: logical [row][col] -> flat row*256 + ((col+row)&255)
#define LDSR(arr, row, col) arr[(((row) << 8) | (((col) + (row)) & 255))]

// ---------------- in-register 16-point inverse DFT (natural in/out) ----------------
__device__ __forceinline__ void fft16_inv(float2* v) {
    const float C1 = 0.92387953251128675613f;   // cos(pi/8)
    const float S1 = 0.38268343236508977173f;   // sin(pi/8)
    const float R2 = 0.70710678118654752440f;   // sqrt(2)/2
    float2 h[16];
#pragma unroll
    for (int b = 0; b < 4; ++b) {
        float2 s02 = caddf(v[b], v[b + 8]);
        float2 d02 = csubf(v[b], v[b + 8]);
        float2 s13 = caddf(v[b + 4], v[b + 12]);
        float2 d13 = csubf(v[b + 4], v[b + 12]);
        float2 id13 = make_float2(-d13.y, d13.x);          // i*d13
        h[4 * b + 0] = caddf(s02, s13);
        h[4 * b + 1] = caddf(d02, id13);
        h[4 * b + 2] = csubf(s02, s13);
        h[4 * b + 3] = csubf(d02, id13);
    }
    h[5]  = cmulw(h[5],  C1,  S1);
    h[6]  = make_float2(R2 * (h[6].x - h[6].y),  R2 * (h[6].x + h[6].y));
    h[7]  = cmulw(h[7],  S1,  C1);
    h[9]  = make_float2(R2 * (h[9].x - h[9].y),  R2 * (h[9].x + h[9].y));
    h[10] = make_float2(-h[10].y, h[10].x);
    h[11] = cmulw(h[11], -R2, R2);
    h[13] = cmulw(h[13], S1,  C1);
    h[14] = cmulw(h[14], -R2, R2);
    h[15] = cmulw(h[15], -C1, -S1);
#pragma unroll
    for (int K1 = 0; K1 < 4; ++K1) {
        float2 a = h[K1], bb = h[4 + K1], cc = h[8 + K1], dd = h[12 + K1];
        float2 sac = caddf(a, cc), dac = csubf(a, cc);
        float2 sbd = caddf(bb, dd), dbd = csubf(bb, dd);
        float2 idbd = make_float2(-dbd.y, dbd.x);
        v[K1]      = caddf(sac, sbd);
        v[K1 + 4]  = caddf(dac, idbd);
        v[K1 + 8]  = csubf(sac, sbd);
        v[K1 + 12] = csubf(dac, idbd);
    }
}

// z-twiddle: v[K1] *= e^{+2pi i q K1/256}
__device__ __forceinline__ void ztwiddle(float2* v, int q) {
    float ss, cc;
    __sincosf((TWOPI_F / 256.0f) * (float)q, &ss, &cc);
    float2 w = make_float2(1.0f, 0.0f), stp = make_float2(cc, ss);
#pragma unroll
    for (int K1 = 0; K1 < 16; ++K1) {
        v[K1] = cmul(v[K1], w);
        w = cmul(w, stp);
    }
}

// ---------------- Kernel Q: partial chain product over stages 1..17 ----------------
__global__ __launch_bounds__(256) void build_q(const float* __restrict__ el,
                                               float2* __restrict__ Q) {
    __shared__ float c_s[18], s_s[18], T_s[18];
    int tid = threadIdx.x;
    if (tid < 18) {
        float e = el[tid];
        float shift1 = e * (1.0f / (float)(1u << tid));
        float sh2 = 1.0f - shift1;                        // THE float32 rounding
        float s = sh2 * (float)(1u << tid);
        float c = (float)(6.2831853071795864769 / (double)((1u << tid) + 1u));
        c_s[tid] = c;
        s_s[tid] = s;
        float p  = (float)(1u << tid) * c;
        float th = p * s;
        float sn, cs; phase_sincos(th, &sn, &cs);
        T_s[tid] = cs;
    }
    __syncthreads();

    unsigned r = blockIdx.x * 256u + (unsigned)tid;       // [0, 2^18)
    if (r == 0u) { Q[0] = make_float2(1.0f, 0.0f); return; }

    unsigned t = (unsigned)__builtin_ctz(r);              // t <= 17
    float Pr = T_s[t], Pi = 0.0f;

#pragma unroll
    for (int i = 1; i <= 17; ++i) {
        unsigned hi = 1u << i;
        int sd = (int)((r + hi) & (2u * hi - 1u)) - (int)hi;
        int K  = (i <= (int)t) ? 0 : (sd < 0 ? -sd : sd);
        float sgn = (sd < 0) ? -1.0f : 1.0f;
        float p  = (float)K * c_s[i];
        float th = p * s_s[i];
        float sn, cs; phase_sincos(th, &sn, &cs);
        float ssn = sgn * sn;
        float nr = Pr * cs - Pi * ssn;
        float ni = Pr * ssn + Pi * cs;
        Pr = nr; Pi = ni;
    }
    Q[r] = make_float2(Pr, Pi);
}

// ---------------- chain factor for stage i at bin k (exact float sequence) ----------------
__device__ __forceinline__ float2 chain_factor(int i, unsigned k,
                                               const float* __restrict__ c_s,
                                               const float* __restrict__ s_s) {
    unsigned hi = 1u << i;
    int sd = (int)((k + hi) & (2u * hi - 1u)) - (int)hi;
    int K  = (sd < 0) ? -sd : sd;
    float sgn = (sd < 0) ? -1.0f : 1.0f;
    float p  = (float)K * c_s[i];
    float th = p * s_s[i];
    float sn, cs; phase_sincos(th, &sn, &cs);
    return make_float2(cs, sgn * sn);
}

// ---------------- chain tail: level-24 factors + c2r pack ----------------
struct WPair { float2 wk, wmk; };

__device__ __forceinline__ WPair chain_tail(unsigned k, float Pr, float Pi,
                                            const float* __restrict__ c_s,
                                            const float* __restrict__ s_s) {
    const float sc = 1.0f / 33554432.0f;                  // 1/N
    unsigned mk = M24 - k;
    float thk = ((float)k  * c_s[24]) * s_s[24];
    float thm = ((float)mk * c_s[24]) * s_s[24];
    float snk, csk, snm, csm;
    phase_sincos(thk, &snk, &csk);
    phase_sincos(thm, &snm, &csm);

    float Skr = Pr * csk - Pi * snk;
    float Ski = Pr * snk + Pi * csk;
    float Smr = Pr * csm + Pi * snm;                      // conj(P) * e^{i*thm}
    float Smi = Pr * snm - Pi * csm;

    float Ar = Skr + Smr, Ai = Ski - Smi;
    float Br = Skr - Smr, Bi = Ski + Smi;
    float ang = (float)k * (TWOPI_F / 33554432.0f);
    float ts, tc; __sincosf(ang, &ts, &tc);
    float Cr = tc * Br - ts * Bi;
    float Ci = ts * Br + tc * Bi;

    WPair w;
    w.wk  = make_float2((Ar - Ci) * sc, (Ai + Cr) * sc);
    w.wmk = make_float2((Ar + Ci) * sc, (Cr - Ai) * sc);
    return w;
}

// ---------------- full chain (fallback for the b==0 special rows) ----------------
__device__ __forceinline__ WPair chain_W(unsigned k,
                                         const float* __restrict__ c_s,
                                         const float* __restrict__ s_s,
                                         const float* __restrict__ T_s,
                                         const float2* __restrict__ Q) {
    unsigned t = (unsigned)__builtin_ctz(k);              // t <= 23
    unsigned r = k & 0x3FFFFu;
    float Pr, Pi;
    if (r != 0u) {
        float2 q = Q[r];
        Pr = q.x; Pi = q.y;
    } else {
        Pr = T_s[t]; Pi = 0.0f;
    }
#pragma unroll
    for (int i = 18; i <= 23; ++i) {
        unsigned hi = 1u << i;
        int sd = (int)((k + hi) & (2u * hi - 1u)) - (int)hi;
        int K  = (i <= (int)t) ? 0 : (sd < 0 ? -sd : sd);
        float sgn = (sd < 0) ? -1.0f : 1.0f;
        float p  = (float)K * c_s[i];
        float th = p * s_s[i];
        float sn, cs; phase_sincos(th, &sn, &cs);
        float ssn = sgn * sn;
        float nr = Pr * cs - Pi * ssn;
        float ni = Pr * ssn + Pi * cs;
        Pr = nr; Pi = ni;
    }
    return chain_tail(k, Pr, Pi, c_s, s_s);
}

// ---------------- row -> column map (mirror-closed block row sets) ----------------
__device__ __forceinline__ int c_of_row(int b, int r) {
    if (b == 0) {
        if (r < 8)  return r;               // 0..7
        if (r == 8) return 32768;           // self-mirrored
        return 65536 - (r - 8);             // r=9..15 -> 65535..65529
    }
    return (r < 8) ? (8 * b + r) : (65536 - 8 * b - (r - 8));
}

// ---------------- Fused: build W (raw in LDS) + radix-16^2 IDFT over k3 ----------------
__global__ __launch_bounds__(256, 3) void fused_build_fft_a(const float* __restrict__ el,
                                                            const float2* __restrict__ Q,
                                                            float2* __restrict__ out) {
    __shared__ float2 lds[16][257];
    __shared__ float c_s[25], s_s[25], T_s[24];
    int tid = threadIdx.x;
    if (tid < 25) {
        float e = el[tid];
        float shift1 = e * (1.0f / (float)(1u << tid));
        float sh2 = 1.0f - shift1;                        // THE float32 rounding
        float s = sh2 * (float)(1u << tid);
        float c = (float)(6.2831853071795864769 / (double)((1u << tid) + 1u));
        c_s[tid] = c;
        s_s[tid] = s;
        if (tid < 24) {
            float p  = (float)(1u << tid) * c;
            float th = p * s;
            float sn, cs; phase_sincos(th, &sn, &cs);
            T_s[tid] = cs;
        }
    }
    __syncthreads();

    int b = xcd_swizzle(blockIdx.x, 4096);
    int r = tid & 15;
    int q = tid >> 4;                                     // [0,16)
    int c = c_of_row(b, r);
    int rm = (b == 0 && (r == 0 || r == 8)) ? r : (r ^ 8);

    if (b == 0 && r == 0) {
        // self-mirrored c=0 row: full chains
#pragma unroll 1
        for (int u = 0; u < 8; ++u) {
            int k3 = q + 16 * u;
            if (k3 == 0) {
                float p  = 16777216.0f * c_s[24];
                float th = p * s_s[24];
                float sn, cs; phase_sincos(th, &sn, &cs);
                const float sc = 1.0f / 33554432.0f;
                lds[0][0] = make_float2((1.0f + cs) * sc, (1.0f - cs) * sc);
                WPair w = chain_W(8388608u, c_s, s_s, T_s, Q);
                lds[0][128] = w.wk;
            } else {
                unsigned j = (unsigned)k3 << 16;
                WPair w = chain_W(j, c_s, s_s, T_s, Q);
                lds[0][k3] = w.wk;
                lds[0][256 - k3] = w.wmk;
            }
        }
    } else {
        // hoisted factor tree: k = kbase + u*2^20, u = 0..7 (bit-exact per k)
        unsigned kbase = (unsigned)c + ((unsigned)q << 16);
        unsigned rres  = kbase & 0x3FFFFu;                // nonzero
        float2 P1 = Q[rres];
        P1 = cmul(P1, chain_factor(18, kbase, c_s, s_s));
        P1 = cmul(P1, chain_factor(19, kbase, c_s, s_s));
        float2 P2[2], P3[4];
#pragma unroll
        for (int j = 0; j < 2; ++j)
            P2[j] = cmul(P1, chain_factor(20, kbase + ((unsigned)j << 20), c_s, s_s));
#pragma unroll
        for (int j = 0; j < 4; ++j)
            P3[j] = cmul(P2[j & 1], chain_factor(21, kbase + ((unsigned)j << 20), c_s, s_s));

#pragma unroll 1
        for (int u = 0; u < 8; ++u) {
            int k3 = q + 16 * u;
            unsigned k = kbase + ((unsigned)u << 20);
            float2 P = cmul(P3[u & 3], chain_factor(22, k, c_s, s_s));
            P = cmul(P, chain_factor(23, k, c_s, s_s));
            WPair w = chain_tail(k, P.x, P.y, c_s, s_s);
            lds[r][k3] = w.wk;
            lds[rm][255 - k3] = w.wmk;
        }
    }
    __syncthreads();

    // phase 1: thread (r,q) owns column n2=q of row r
    float2 v[16];
#pragma unroll
    for (int n1 = 0; n1 < 16; ++n1) v[n1] = lds[r][q + 16 * n1];
    fft16_inv(v);
    ztwiddle(v, q);
#pragma unroll
    for (int K1 = 0; K1 < 16; ++K1) lds[r][K1 * 16 + q] = v[K1];   // own slot set
    __syncthreads();

    // phase 2: thread (r,q) owns K1=q; output t3 = q + 16*K2 (natural order)
#pragma unroll
    for (int n2 = 0; n2 < 16; ++n2) v[n2] = lds[r][q * 16 + n2];
    fft16_inv(v);
#pragma unroll
    for (int K2 = 0; K2 < 16; ++K2)
        out[c + ((q + 16 * K2) << 16)] = v[K2];
}

// ---------------- Stage B: 32 k1 x 256 k2 tile, fixed t3 ----------------
// Reads L1 = c + 65536*t3 (256-B chunks); writes L2 = t2*65536 + t3*256 + k1
// (256-B chunks). One barrier.
__global__ __launch_bounds__(512, 4) void fft_stage_b(const float2* __restrict__ in,
                                                      float2* __restrict__ out) {
    __shared__ float2 ldsf[8192];                         // 64 KiB, rotated layout
    int tid = threadIdx.x;
    int wg  = xcd_swizzle(blockIdx.x, 2048);
    int k1b = (wg & 7) * 32;
    int t3  = wg >> 3;
    int row = tid & 31;                                   // local k1
    int q   = tid >> 5;                                   // [0,16)
    const float tsc = TWOPI_F / 65536.0f;

    float2 v[16];
    const float2* src = in + (k1b + row + (q << 8) + (t3 << 16));
#pragma unroll
    for (int u = 0; u < 16; ++u) v[u] = src[u << 12];     // k2 = q + 16u

    {   // inter-stage twiddle e^{+i tsc t3 k2}
        float sb, cb; __sincosf(tsc * (float)(t3 * q), &sb, &cb);
        float ssx, csx; __sincosf(tsc * (float)(t3 * 16), &ssx, &csx);
        float2 w = make_float2(cb, sb), stp = make_float2(csx, ssx);
#pragma unroll
        for (int u = 0; u < 16; ++u) {
            v[u] = cmul(v[u], w);
            w = cmul(w, stp);
        }
    }
    fft16_inv(v);
    ztwiddle(v, q);
#pragma unroll
    for (int K1 = 0; K1 < 16; ++K1) LDSR(ldsf, row, K1 * 16 + q) = v[K1];  // own cols (== q mod 16)
    __syncthreads();

#pragma unroll
    for (int n2 = 0; n2 < 16; ++n2) v[n2] = LDSR(ldsf, row, q * 16 + n2);
    fft16_inv(v);
    // t2 = q + 16*K2
#pragma unroll
    for (int K2 = 0; K2 < 16; ++K2)
        out[((q + 16 * K2) << 16) + (t3 << 8) + (k1b + row)] = v[K2];
}

// ---------------- Stage C: 32 t3 x 256 k1 tile, fixed t2 ----------------
// Reads L2 as a contiguous 64-KB slab; writes out n = t3 + 256*t2 + 65536*t1
// (256-B chunks). Two barriers.
__global__ __launch_bounds__(512, 4) void fft_stage_c(const float2* __restrict__ in,
                                                      float2* __restrict__ out) {
    __shared__ float2 ldsf[8192];                         // 64 KiB, rotated layout
    int tid = threadIdx.x;
    int wg  = xcd_swizzle(blockIdx.x, 2048);
    int t3b = (wg & 7) * 32;
    int t2  = wg >> 3;
    const float tsc = TWOPI_F / 16777216.0f;

    // stage the contiguous slab: addr = t2*65536 + (t3b+row)*256 + k1
    const float2* src = in + ((t2 << 16) + (t3b << 8));
#pragma unroll
    for (int i = 0; i < 16; ++i) {
        int f = tid + 512 * i;                            // f = row*256 + k1
        LDSR(ldsf, f >> 8, f & 255) = src[f];
    }
    __syncthreads();

    int row = tid & 31;                                   // local t3
    int q   = tid >> 5;                                   // [0,16)
    int t3  = t3b + row;
    int A   = t3 + (t2 << 8);                             // < 2^16
    float2 v[16];
    {   // phase-1 load + twiddle e^{+i tsc A k1}, k1 = q + 16*n1
        float sb, cb; __sincosf(tsc * (float)(A * q), &sb, &cb);
        float ssx, csx; __sincosf(tsc * (float)(A * 16), &ssx, &csx);
        float2 w = make_float2(cb, sb), stp = make_float2(csx, ssx);
#pragma unroll
        for (int n1 = 0; n1 < 16; ++n1) {
            v[n1] = cmul(LDSR(ldsf, row, q + 16 * n1), w);
            w = cmul(w, stp);
        }
    }
    fft16_inv(v);
    ztwiddle(v, q);
#pragma unroll
    for (int K1 = 0; K1 < 16; ++K1) LDSR(ldsf, row, K1 * 16 + q) = v[K1];  // own cols
    __syncthreads();

#pragma unroll
    for (int n2 = 0; n2 < 16; ++n2) v[n2] = LDSR(ldsf, row, q * 16 + n2);
    fft16_inv(v);
    // t1 = q + 16*K2 ; n = t3 + 256*t2 + 65536*t1
#pragma unroll
    for (int K2 = 0; K2 < 16; ++K2)
        out[((q + 16 * K2) << 16) + (t2 << 8) + t3] = v[K2];
}

extern "C" void kernel_launch(void* const* d_in, const int* in_sizes, int n_in,
                              void* d_out, int out_size, void* d_ws, size_t ws_size,
                              hipStream_t stream) {
    const float* el = (const float*)d_in[0];   // 25 floats
    float2* Gd = (float2*)d_out;               // out buffer doubles as complex ping-pong
    float2* Q  = (float2*)d_ws;                // Q table (2 MiB) lives in ws until stage B

    // build_q (ws) -> fusedA: (chains+FFT) -> out -> stageB: out->ws (clobbers Q, ok)
    // -> stageC: ws->out (final real signal)
    hipLaunchKernelGGL(build_q,           dim3(1024), dim3(256), 0, stream, el, Q);
    hipLaunchKernelGGL(fused_build_fft_a, dim3(4096), dim3(256), 0, stream, el, Q, Gd);
    hipLaunchKernelGGL(fft_stage_b,       dim3(2048), dim3(512), 0, stream, Gd, (float2*)d_ws);
    hipLaunchKernelGGL(fft_stage_c,       dim3(2048), dim3(512), 0, stream, (float2*)d_ws, Gd);
}

// Round 6
// 267.213 us; speedup vs baseline: 1.0371x; 1.0371x over previous
//
#include <hip/hip_runtime.h>

// HiearchicalFFTShiftModel: closed-form spectrum with EXACT emulation of the
// reference's complex64 phase quantization, + fused chain+FFT pass and two
// transpose-FFT passes over 2^24 complex points (c2r packing).
//
// Round-6 change vs 271us: HIP's __sincosf is the PRECISE OCML sincos
// (~60-80 instrs, no fast variant) - calibrated at ~113 cyc per phase_sincos
// from round-0 counters vs ~45 expected native. Since phase_sincos already
// reduces mod 2*pi in double, feed the fraction (REVOLUTIONS) directly to
// v_sin_f32/v_cos_f32 (__builtin_amdgcn_sinf/cosf: D=sin(S0*2pi)). All other
// twiddle sites use sincos_rev with exactly-scaled pow2 arguments in [-0.5,1).
// The double-precision phase reduction (the reference-emulation part) is
// unchanged; only the final sin/cos evaluation differs (~1e-7) -> absmax
// expected to move within O(1e-5). B/C reverted to round-4 forms (measured
// best). A gets __launch_bounds__(256,4).

constexpr float TWOPI_F = 6.28318530717958647692f;
constexpr unsigned M24 = 1u << 24;

// th in radians (|th| up to ~1.1e8): reduce mod 2*pi in DOUBLE (exactly as the
// previous rounds - this ordering is part of the verified numerics), then
// evaluate with the native HW trig ops, which take REVOLUTIONS.
__device__ __forceinline__ void phase_sincos(float th, float* sn, float* cs) {
    double d = (double)th * 0.15915494309189533577;  // 1/(2*pi)
    d -= rint(d);                                    // frac in [-0.5, 0.5]
    float r = (float)d;                              // revolutions
    *sn = __builtin_amdgcn_sinf(r);                  // v_sin_f32: sin(2*pi*r)
    *cs = __builtin_amdgcn_cosf(r);                  // v_cos_f32: cos(2*pi*r)
}

// rev already in revolutions, |rev| < ~1: cheap f32 reduction + native trig.
__device__ __forceinline__ void sincos_rev(float rev, float* sn, float* cs) {
    float r = rev - rintf(rev);                      // [-0.5, 0.5]
    *sn = __builtin_amdgcn_sinf(r);
    *cs = __builtin_amdgcn_cosf(r);
}

__device__ __forceinline__ float2 cmul(float2 a, float2 f) {
    return make_float2(a.x * f.x - a.y * f.y, a.x * f.y + a.y * f.x);
}
__device__ __forceinline__ float2 caddf(float2 a, float2 b) { return make_float2(a.x + b.x, a.y + b.y); }
__device__ __forceinline__ float2 csubf(float2 a, float2 b) { return make_float2(a.x - b.x, a.y - b.y); }
__device__ __forceinline__ float2 cmulw(float2 a, float c, float s) {
    return make_float2(a.x * c - a.y * s, a.x * s + a.y * c);
}

// chunked bijective XCD swizzle (nblocks divisible by 8)
__device__ __forceinline__ int xcd_swizzle(int b, int nblocks) {
    int chunk = nblocks >> 3;
    return (b & 7) * chunk + (b >> 3);
}

// ---------------- in-register 16-point inverse DFT (natural in/out) ----------------
__device__ __forceinline__ void fft16_inv(float2* v) {
    const float C1 = 0.92387953251128675613f;   // cos(pi/8)
    const float S1 = 0.38268343236508977173f;   // sin(pi/8)
    const float R2 = 0.70710678118654752440f;   // sqrt(2)/2
    float2 h[16];
#pragma unroll
    for (int b = 0; b < 4; ++b) {
        float2 s02 = caddf(v[b], v[b + 8]);
        float2 d02 = csubf(v[b], v[b + 8]);
        float2 s13 = caddf(v[b + 4], v[b + 12]);
        float2 d13 = csubf(v[b + 4], v[b + 12]);
        float2 id13 = make_float2(-d13.y, d13.x);          // i*d13
        h[4 * b + 0] = caddf(s02, s13);
        h[4 * b + 1] = caddf(d02, id13);
        h[4 * b + 2] = csubf(s02, s13);
        h[4 * b + 3] = csubf(d02, id13);
    }
    h[5]  = cmulw(h[5],  C1,  S1);
    h[6]  = make_float2(R2 * (h[6].x - h[6].y),  R2 * (h[6].x + h[6].y));
    h[7]  = cmulw(h[7],  S1,  C1);
    h[9]  = make_float2(R2 * (h[9].x - h[9].y),  R2 * (h[9].x + h[9].y));
    h[10] = make_float2(-h[10].y, h[10].x);
    h[11] = cmulw(h[11], -R2, R2);
    h[13] = cmulw(h[13], S1,  C1);
    h[14] = cmulw(h[14], -R2, R2);
    h[15] = cmulw(h[15], -C1, -S1);
#pragma unroll
    for (int K1 = 0; K1 < 4; ++K1) {
        float2 a = h[K1], bb = h[4 + K1], cc = h[8 + K1], dd = h[12 + K1];
        float2 sac = caddf(a, cc), dac = csubf(a, cc);
        float2 sbd = caddf(bb, dd), dbd = csubf(bb, dd);
        float2 idbd = make_float2(-dbd.y, dbd.x);
        v[K1]      = caddf(sac, sbd);
        v[K1 + 4]  = caddf(dac, idbd);
        v[K1 + 8]  = csubf(sac, sbd);
        v[K1 + 12] = csubf(dac, idbd);
    }
}

// z-twiddle: v[K1] *= e^{+2pi i q K1/256}
__device__ __forceinline__ void ztwiddle(float2* v, int q) {
    float ss, cc;
    sincos_rev((float)q * (1.0f / 256.0f), &ss, &cc);
    float2 w = make_float2(1.0f, 0.0f), stp = make_float2(cc, ss);
#pragma unroll
    for (int K1 = 0; K1 < 16; ++K1) {
        v[K1] = cmul(v[K1], w);
        w = cmul(w, stp);
    }
}

// ---------------- Kernel Q: partial chain product over stages 1..17 ----------------
__global__ __launch_bounds__(256) void build_q(const float* __restrict__ el,
                                               float2* __restrict__ Q) {
    __shared__ float c_s[18], s_s[18], T_s[18];
    int tid = threadIdx.x;
    if (tid < 18) {
        float e = el[tid];
        float shift1 = e * (1.0f / (float)(1u << tid));
        float sh2 = 1.0f - shift1;                        // THE float32 rounding
        float s = sh2 * (float)(1u << tid);
        float c = (float)(6.2831853071795864769 / (double)((1u << tid) + 1u));
        c_s[tid] = c;
        s_s[tid] = s;
        float p  = (float)(1u << tid) * c;
        float th = p * s;
        float sn, cs; phase_sincos(th, &sn, &cs);
        T_s[tid] = cs;
    }
    __syncthreads();

    unsigned r = blockIdx.x * 256u + (unsigned)tid;       // [0, 2^18)
    if (r == 0u) { Q[0] = make_float2(1.0f, 0.0f); return; }

    unsigned t = (unsigned)__builtin_ctz(r);              // t <= 17
    float Pr = T_s[t], Pi = 0.0f;

#pragma unroll
    for (int i = 1; i <= 17; ++i) {
        unsigned hi = 1u << i;
        int sd = (int)((r + hi) & (2u * hi - 1u)) - (int)hi;
        int K  = (i <= (int)t) ? 0 : (sd < 0 ? -sd : sd);
        float sgn = (sd < 0) ? -1.0f : 1.0f;
        float p  = (float)K * c_s[i];
        float th = p * s_s[i];
        float sn, cs; phase_sincos(th, &sn, &cs);
        float ssn = sgn * sn;
        float nr = Pr * cs - Pi * ssn;
        float ni = Pr * ssn + Pi * cs;
        Pr = nr; Pi = ni;
    }
    Q[r] = make_float2(Pr, Pi);
}

// ---------------- chain factor for stage i at bin k (exact float sequence) ----------------
__device__ __forceinline__ float2 chain_factor(int i, unsigned k,
                                               const float* __restrict__ c_s,
                                               const float* __restrict__ s_s) {
    unsigned hi = 1u << i;
    int sd = (int)((k + hi) & (2u * hi - 1u)) - (int)hi;
    int K  = (sd < 0) ? -sd : sd;
    float sgn = (sd < 0) ? -1.0f : 1.0f;
    float p  = (float)K * c_s[i];
    float th = p * s_s[i];
    float sn, cs; phase_sincos(th, &sn, &cs);
    return make_float2(cs, sgn * sn);
}

// ---------------- chain tail: level-24 factors + c2r pack ----------------
struct WPair { float2 wk, wmk; };

__device__ __forceinline__ WPair chain_tail(unsigned k, float Pr, float Pi,
                                            const float* __restrict__ c_s,
                                            const float* __restrict__ s_s) {
    const float sc = 1.0f / 33554432.0f;                  // 1/N
    unsigned mk = M24 - k;
    float thk = ((float)k  * c_s[24]) * s_s[24];
    float thm = ((float)mk * c_s[24]) * s_s[24];
    float snk, csk, snm, csm;
    phase_sincos(thk, &snk, &csk);
    phase_sincos(thm, &snm, &csm);

    float Skr = Pr * csk - Pi * snk;
    float Ski = Pr * snk + Pi * csk;
    float Smr = Pr * csm + Pi * snm;                      // conj(P) * e^{i*thm}
    float Smi = Pr * snm - Pi * csm;

    float Ar = Skr + Smr, Ai = Ski - Smi;
    float Br = Skr - Smr, Bi = Ski + Smi;
    float ts, tc;
    sincos_rev((float)k * (1.0f / 33554432.0f), &ts, &tc);   // k <= 2^23: exact
    float Cr = tc * Br - ts * Bi;
    float Ci = ts * Br + tc * Bi;

    WPair w;
    w.wk  = make_float2((Ar - Ci) * sc, (Ai + Cr) * sc);
    w.wmk = make_float2((Ar + Ci) * sc, (Cr - Ai) * sc);
    return w;
}

// ---------------- full chain (fallback for the b==0 special rows) ----------------
__device__ __forceinline__ WPair chain_W(unsigned k,
                                         const float* __restrict__ c_s,
                                         const float* __restrict__ s_s,
                                         const float* __restrict__ T_s,
                                         const float2* __restrict__ Q) {
    unsigned t = (unsigned)__builtin_ctz(k);              // t <= 23
    unsigned r = k & 0x3FFFFu;
    float Pr, Pi;
    if (r != 0u) {
        float2 q = Q[r];
        Pr = q.x; Pi = q.y;
    } else {
        Pr = T_s[t]; Pi = 0.0f;
    }
#pragma unroll
    for (int i = 18; i <= 23; ++i) {
        unsigned hi = 1u << i;
        int sd = (int)((k + hi) & (2u * hi - 1u)) - (int)hi;
        int K  = (i <= (int)t) ? 0 : (sd < 0 ? -sd : sd);
        float sgn = (sd < 0) ? -1.0f : 1.0f;
        float p  = (float)K * c_s[i];
        float th = p * s_s[i];
        float sn, cs; phase_sincos(th, &sn, &cs);
        float ssn = sgn * sn;
        float nr = Pr * cs - Pi * ssn;
        float ni = Pr * ssn + Pi * cs;
        Pr = nr; Pi = ni;
    }
    return chain_tail(k, Pr, Pi, c_s, s_s);
}

// ---------------- row -> column map (mirror-closed block row sets) ----------------
__device__ __forceinline__ int c_of_row(int b, int r) {
    if (b == 0) {
        if (r < 8)  return r;               // 0..7
        if (r == 8) return 32768;           // self-mirrored
        return 65536 - (r - 8);             // r=9..15 -> 65535..65529
    }
    return (r < 8) ? (8 * b + r) : (65536 - 8 * b - (r - 8));
}

// ---------------- Fused: build W (raw in LDS) + radix-16^2 IDFT over k3 ----------------
__global__ __launch_bounds__(256, 4) void fused_build_fft_a(const float* __restrict__ el,
                                                            const float2* __restrict__ Q,
                                                            float2* __restrict__ out) {
    __shared__ float2 lds[16][257];
    __shared__ float c_s[25], s_s[25], T_s[24];
    int tid = threadIdx.x;
    if (tid < 25) {
        float e = el[tid];
        float shift1 = e * (1.0f / (float)(1u << tid));
        float sh2 = 1.0f - shift1;                        // THE float32 rounding
        float s = sh2 * (float)(1u << tid);
        float c = (float)(6.2831853071795864769 / (double)((1u << tid) + 1u));
        c_s[tid] = c;
        s_s[tid] = s;
        if (tid < 24) {
            float p  = (float)(1u << tid) * c;
            float th = p * s;
            float sn, cs; phase_sincos(th, &sn, &cs);
            T_s[tid] = cs;
        }
    }
    __syncthreads();

    int b = xcd_swizzle(blockIdx.x, 4096);
    int r = tid & 15;
    int q = tid >> 4;                                     // [0,16)
    int c = c_of_row(b, r);
    int rm = (b == 0 && (r == 0 || r == 8)) ? r : (r ^ 8);

    if (b == 0 && r == 0) {
        // self-mirrored c=0 row: full chains
#pragma unroll 1
        for (int u = 0; u < 8; ++u) {
            int k3 = q + 16 * u;
            if (k3 == 0) {
                float p  = 16777216.0f * c_s[24];
                float th = p * s_s[24];
                float sn, cs; phase_sincos(th, &sn, &cs);
                const float sc = 1.0f / 33554432.0f;
                lds[0][0] = make_float2((1.0f + cs) * sc, (1.0f - cs) * sc);
                WPair w = chain_W(8388608u, c_s, s_s, T_s, Q);
                lds[0][128] = w.wk;
            } else {
                unsigned j = (unsigned)k3 << 16;
                WPair w = chain_W(j, c_s, s_s, T_s, Q);
                lds[0][k3] = w.wk;
                lds[0][256 - k3] = w.wmk;
            }
        }
    } else {
        // hoisted factor tree: k = kbase + u*2^20, u = 0..7 (same float seq per k)
        unsigned kbase = (unsigned)c + ((unsigned)q << 16);
        unsigned rres  = kbase & 0x3FFFFu;                // nonzero
        float2 P1 = Q[rres];
        P1 = cmul(P1, chain_factor(18, kbase, c_s, s_s));
        P1 = cmul(P1, chain_factor(19, kbase, c_s, s_s));
        float2 P2[2], P3[4];
#pragma unroll
        for (int j = 0; j < 2; ++j)
            P2[j] = cmul(P1, chain_factor(20, kbase + ((unsigned)j << 20), c_s, s_s));
#pragma unroll
        for (int j = 0; j < 4; ++j)
            P3[j] = cmul(P2[j & 1], chain_factor(21, kbase + ((unsigned)j << 20), c_s, s_s));

#pragma unroll 1
        for (int u = 0; u < 8; ++u) {
            int k3 = q + 16 * u;
            unsigned k = kbase + ((unsigned)u << 20);
            float2 P = cmul(P3[u & 3], chain_factor(22, k, c_s, s_s));
            P = cmul(P, chain_factor(23, k, c_s, s_s));
            WPair w = chain_tail(k, P.x, P.y, c_s, s_s);
            lds[r][k3] = w.wk;
            lds[rm][255 - k3] = w.wmk;
        }
    }
    __syncthreads();

    // phase 1: thread (r,q) owns column n2=q of row r
    float2 v[16];
#pragma unroll
    for (int n1 = 0; n1 < 16; ++n1) v[n1] = lds[r][q + 16 * n1];
    fft16_inv(v);
    ztwiddle(v, q);
#pragma unroll
    for (int K1 = 0; K1 < 16; ++K1) lds[r][K1 * 16 + q] = v[K1];   // own slot set
    __syncthreads();

    // phase 2: thread (r,q) owns K1=q; output t3 = q + 16*K2 (natural order)
#pragma unroll
    for (int n2 = 0; n2 < 16; ++n2) v[n2] = lds[r][q * 16 + n2];
    fft16_inv(v);
#pragma unroll
    for (int K2 = 0; K2 < 16; ++K2)
        out[c + ((q + 16 * K2) << 16)] = v[K2];
}

// ---------------- Stage B: twiddle + radix-16^2 IDFT over k2 (stride 256) ----------------
__global__ __launch_bounds__(256, 3) void fft_stage_b(const float2* __restrict__ in,
                                                      float2* __restrict__ out) {
    __shared__ float2 lds[16][257];
    int tid = threadIdx.x;
    int wg  = xcd_swizzle(blockIdx.x, 4096);
    int k1b = (wg & 15) * 16;
    int t3  = wg >> 4;
    int row = tid & 15;
    int q   = tid >> 4;                                   // n2 = q; loads ARE the phase-1 set

    float2 v[16];
    const float2* src = in + (k1b + row + (q << 8) + (t3 << 16));
#pragma unroll
    for (int u = 0; u < 16; ++u) v[u] = src[u << 12];     // k2 = q + 16u

    {   // inter-stage twiddle e^{+2pi i t3 k2 / 65536}
        float sb, cb; sincos_rev((float)(t3 * q)  * (1.0f / 65536.0f), &sb, &cb);
        float ssx, csx; sincos_rev((float)t3 * (1.0f / 4096.0f), &ssx, &csx);
        float2 w = make_float2(cb, sb), stp = make_float2(csx, ssx);
#pragma unroll
        for (int u = 0; u < 16; ++u) {
            v[u] = cmul(v[u], w);
            w = cmul(w, stp);
        }
    }
    fft16_inv(v);
    ztwiddle(v, q);
#pragma unroll
    for (int K1 = 0; K1 < 16; ++K1) lds[row][K1 * 16 + q] = v[K1];
    __syncthreads();

#pragma unroll
    for (int n2 = 0; n2 < 16; ++n2) v[n2] = lds[row][q * 16 + n2];
    fft16_inv(v);
#pragma unroll
    for (int K2 = 0; K2 < 16; ++K2)
        out[k1b + row + ((q + 16 * K2) << 8) + (t3 << 16)] = v[K2];
}

// ---------------- Stage C: twiddle + radix-16^2 IDFT over k1 (stride 1) ----------------
__global__ __launch_bounds__(256, 3) void fft_stage_c(const float2* __restrict__ in,
                                                      float2* __restrict__ out) {
    __shared__ float2 lds[16][257];
    int tid = threadIdx.x;
    int wg  = xcd_swizzle(blockIdx.x, 4096);
    int t3b = (wg & 15) * 16;
    int t2  = wg >> 4;

    {   // load one k1 column across 16 rows, twiddle, raw-stage to LDS
        int k1 = tid;
        const float2* src = in + (k1 + (t2 << 8) + (t3b << 16));
        float2 vb[16];
#pragma unroll
        for (int u = 0; u < 16; ++u) vb[u] = src[u << 16];
        int base = (t3b + (t2 << 8)) * k1;                // < 2^24, exact in float
        float sb, cb; sincos_rev((float)base * (1.0f / 16777216.0f), &sb, &cb);
        float ssx, csx; sincos_rev((float)k1 * (1.0f / 1048576.0f), &ssx, &csx);  // 16/2^24
        float2 w = make_float2(cb, sb), stp = make_float2(csx, ssx);
#pragma unroll
        for (int u = 0; u < 16; ++u) {
            lds[u][k1] = cmul(vb[u], w);
            w = cmul(w, stp);
        }
    }
    __syncthreads();

    int rr = tid & 15;
    int q  = tid >> 4;
    float2 v[16];
#pragma unroll
    for (int n1 = 0; n1 < 16; ++n1) v[n1] = lds[rr][q + 16 * n1];
    fft16_inv(v);
    ztwiddle(v, q);
#pragma unroll
    for (int K1 = 0; K1 < 16; ++K1) lds[rr][K1 * 16 + q] = v[K1];  // own slot set
    __syncthreads();

#pragma unroll
    for (int n2 = 0; n2 < 16; ++n2) v[n2] = lds[rr][q * 16 + n2];
    fft16_inv(v);
#pragma unroll
    for (int K2 = 0; K2 < 16; ++K2)
        out[(t3b + rr) + (t2 << 8) + ((q + 16 * K2) << 16)] = v[K2];
}

extern "C" void kernel_launch(void* const* d_in, const int* in_sizes, int n_in,
                              void* d_out, int out_size, void* d_ws, size_t ws_size,
                              hipStream_t stream) {
    const float* el = (const float*)d_in[0];   // 25 floats
    float2* Gd = (float2*)d_out;               // out buffer doubles as complex ping-pong
    float2* Q  = (float2*)d_ws;                // Q table (2 MiB) lives in ws until stage B

    // build_q (ws) -> fusedA: (chains+FFT) -> out -> stageB: out->ws (clobbers Q, ok)
    // -> stageC: ws->out (final real signal)
    hipLaunchKernelGGL(build_q,           dim3(1024), dim3(256), 0, stream, el, Q);
    hipLaunchKernelGGL(fused_build_fft_a, dim3(4096), dim3(256), 0, stream, el, Q, Gd);
    hipLaunchKernelGGL(fft_stage_b,       dim3(4096), dim3(256), 0, stream, Gd, (float2*)d_ws);
    hipLaunchKernelGGL(fft_stage_c,       dim3(4096), dim3(256), 0, stream, (float2*)d_ws, Gd);
}

// Round 7
// 255.339 us; speedup vs baseline: 1.0853x; 1.0465x over previous
//
#include <hip/hip_runtime.h>

// HiearchicalFFTShiftModel: closed-form spectrum with EXACT emulation of the
// reference's complex64 phase quantization, + fused chain+FFT pass and two
// transpose-FFT passes over 2^24 complex points (c2r packing).
//
// Round-7 change vs 267us: budget audit shows a ~78us constant (ws re-poison
// fill) inside the timed region; kernels are A~70 B~56 C~56 q~2. A's gap to
// its ~40us floor is its 64-B-granular scattered stores (8+8 mirror columns
// per block; round-2 WRITE_SIZE 168MB vs 134 ideal). Fix: 32-column tile
// (16 consecutive + 16 mirror-consecutive, 512 threads, 64-KiB LDS with
// per-row rotation instead of padding, 2048 blocks) -> every wave stores
// 4x128-B contiguous chunks. Chain hoist tree re-based on k-step 2^21
// (18/19/20 const, 21 2-way, 22 4-way, 23 per-u; 41 sincos/thread), same
// per-k float sequence -> absmax must stay exactly 1.220703e-4.
// B, C, build_q identical to round 6.

constexpr float TWOPI_F = 6.28318530717958647692f;
constexpr unsigned M24 = 1u << 24;
constexpr double TPD = 6.2831853071795864769;

// th in radians: reduce mod 2*pi in DOUBLE (verified numerics), evaluate with
// native HW trig (takes REVOLUTIONS).
__device__ __forceinline__ void phase_sincos(float th, float* sn, float* cs) {
    double d = (double)th * 0.15915494309189533577;  // 1/(2*pi)
    d -= rint(d);                                    // frac in [-0.5, 0.5]
    float r = (float)d;
    *sn = __builtin_amdgcn_sinf(r);
    *cs = __builtin_amdgcn_cosf(r);
}

__device__ __forceinline__ void sincos_rev(float rev, float* sn, float* cs) {
    float r = rev - rintf(rev);
    *sn = __builtin_amdgcn_sinf(r);
    *cs = __builtin_amdgcn_cosf(r);
}

__device__ __forceinline__ float2 cmul(float2 a, float2 f) {
    return make_float2(a.x * f.x - a.y * f.y, a.x * f.y + a.y * f.x);
}
__device__ __forceinline__ float2 caddf(float2 a, float2 b) { return make_float2(a.x + b.x, a.y + b.y); }
__device__ __forceinline__ float2 csubf(float2 a, float2 b) { return make_float2(a.x - b.x, a.y - b.y); }
__device__ __forceinline__ float2 cmulw(float2 a, float c, float s) {
    return make_float2(a.x * c - a.y * s, a.x * s + a.y * c);
}

// chunked bijective XCD swizzle (nblocks divisible by 8)
__device__ __forceinline__ int xcd_swizzle(int b, int nblocks) {
    int chunk = nblocks >> 3;
    return (b & 7) * chunk + (b >> 3);
}

// c_i = (float)(2pi/(2^i+1)) — compile-time table (identical to prior c_s[i]).
__device__ __forceinline__ float c_of(int i) {
    switch (i) {
    case 0:  return (float)(TPD / 2.0);
    case 1:  return (float)(TPD / 3.0);
    case 2:  return (float)(TPD / 5.0);
    case 3:  return (float)(TPD / 9.0);
    case 4:  return (float)(TPD / 17.0);
    case 5:  return (float)(TPD / 33.0);
    case 6:  return (float)(TPD / 65.0);
    case 7:  return (float)(TPD / 129.0);
    case 8:  return (float)(TPD / 257.0);
    case 9:  return (float)(TPD / 513.0);
    case 10: return (float)(TPD / 1025.0);
    case 11: return (float)(TPD / 2049.0);
    case 12: return (float)(TPD / 4097.0);
    case 13: return (float)(TPD / 8193.0);
    case 14: return (float)(TPD / 16385.0);
    case 15: return (float)(TPD / 32769.0);
    case 16: return (float)(TPD / 65537.0);
    case 17: return (float)(TPD / 131073.0);
    case 18: return (float)(TPD / 262145.0);
    case 19: return (float)(TPD / 524289.0);
    case 20: return (float)(TPD / 1048577.0);
    case 21: return (float)(TPD / 2097153.0);
    case 22: return (float)(TPD / 4194305.0);
    case 23: return (float)(TPD / 8388609.0);
    default: return (float)(TPD / 16777217.0);
    }
}

// s_i from elements (identical float ops to prior s_s[i] init)
__device__ __forceinline__ float s_of(const float* __restrict__ el, int i) {
    float e = el[i];
    float shift1 = e * (1.0f / (float)(1u << i));   // exact (pow2 scale)
    float sh2 = 1.0f - shift1;                      // THE float32 rounding
    return sh2 * (float)(1u << i);                  // exact
}

// ---------------- in-register 16-point inverse DFT (natural in/out) ----------------
__device__ __forceinline__ void fft16_inv(float2* v) {
    const float C1 = 0.92387953251128675613f;   // cos(pi/8)
    const float S1 = 0.38268343236508977173f;   // sin(pi/8)
    const float R2 = 0.70710678118654752440f;   // sqrt(2)/2
    float2 h[16];
#pragma unroll
    for (int b = 0; b < 4; ++b) {
        float2 s02 = caddf(v[b], v[b + 8]);
        float2 d02 = csubf(v[b], v[b + 8]);
        float2 s13 = caddf(v[b + 4], v[b + 12]);
        float2 d13 = csubf(v[b + 4], v[b + 12]);
        float2 id13 = make_float2(-d13.y, d13.x);          // i*d13
        h[4 * b + 0] = caddf(s02, s13);
        h[4 * b + 1] = caddf(d02, id13);
        h[4 * b + 2] = csubf(s02, s13);
        h[4 * b + 3] = csubf(d02, id13);
    }
    h[5]  = cmulw(h[5],  C1,  S1);
    h[6]  = make_float2(R2 * (h[6].x - h[6].y),  R2 * (h[6].x + h[6].y));
    h[7]  = cmulw(h[7],  S1,  C1);
    h[9]  = make_float2(R2 * (h[9].x - h[9].y),  R2 * (h[9].x + h[9].y));
    h[10] = make_float2(-h[10].y, h[10].x);
    h[11] = cmulw(h[11], -R2, R2);
    h[13] = cmulw(h[13], S1,  C1);
    h[14] = cmulw(h[14], -R2, R2);
    h[15] = cmulw(h[15], -C1, -S1);
#pragma unroll
    for (int K1 = 0; K1 < 4; ++K1) {
        float2 a = h[K1], bb = h[4 + K1], cc = h[8 + K1], dd = h[12 + K1];
        float2 sac = caddf(a, cc), dac = csubf(a, cc);
        float2 sbd = caddf(bb, dd), dbd = csubf(bb, dd);
        float2 idbd = make_float2(-dbd.y, dbd.x);
        v[K1]      = caddf(sac, sbd);
        v[K1 + 4]  = caddf(dac, idbd);
        v[K1 + 8]  = csubf(sac, sbd);
        v[K1 + 12] = csubf(dac, idbd);
    }
}

// z-twiddle: v[K1] *= e^{+2pi i q K1/256}
__device__ __forceinline__ void ztwiddle(float2* v, int q) {
    float ss, cc;
    sincos_rev((float)q * (1.0f / 256.0f), &ss, &cc);
    float2 w = make_float2(1.0f, 0.0f), stp = make_float2(cc, ss);
#pragma unroll
    for (int K1 = 0; K1 < 16; ++K1) {
        v[K1] = cmul(v[K1], w);
        w = cmul(w, stp);
    }
}

// ---------------- Kernel Q: partial chain product over stages 1..17 ----------------
__global__ __launch_bounds__(256) void build_q(const float* __restrict__ el,
                                               float2* __restrict__ Q) {
    __shared__ float c_s[18], s_s[18], T_s[18];
    int tid = threadIdx.x;
    if (tid < 18) {
        float e = el[tid];
        float shift1 = e * (1.0f / (float)(1u << tid));
        float sh2 = 1.0f - shift1;                        // THE float32 rounding
        float s = sh2 * (float)(1u << tid);
        float c = (float)(6.2831853071795864769 / (double)((1u << tid) + 1u));
        c_s[tid] = c;
        s_s[tid] = s;
        float p  = (float)(1u << tid) * c;
        float th = p * s;
        float sn, cs; phase_sincos(th, &sn, &cs);
        T_s[tid] = cs;
    }
    __syncthreads();

    unsigned r = blockIdx.x * 256u + (unsigned)tid;       // [0, 2^18)
    if (r == 0u) { Q[0] = make_float2(1.0f, 0.0f); return; }

    unsigned t = (unsigned)__builtin_ctz(r);              // t <= 17
    float Pr = T_s[t], Pi = 0.0f;

#pragma unroll
    for (int i = 1; i <= 17; ++i) {
        unsigned hi = 1u << i;
        int sd = (int)((r + hi) & (2u * hi - 1u)) - (int)hi;
        int K  = (i <= (int)t) ? 0 : (sd < 0 ? -sd : sd);
        float sgn = (sd < 0) ? -1.0f : 1.0f;
        float p  = (float)K * c_s[i];
        float th = p * s_s[i];
        float sn, cs; phase_sincos(th, &sn, &cs);
        float ssn = sgn * sn;
        float nr = Pr * cs - Pi * ssn;
        float ni = Pr * ssn + Pi * cs;
        Pr = nr; Pi = ni;
    }
    Q[r] = make_float2(Pr, Pi);
}

// ---------------- chain factor for stage i at bin k (exact float sequence) ----------------
__device__ __forceinline__ float2 cfac(int i, unsigned k, float ci, float si) {
    unsigned hi = 1u << i;
    int sd = (int)((k + hi) & (2u * hi - 1u)) - (int)hi;
    int K  = (sd < 0) ? -sd : sd;
    float sgn = (sd < 0) ? -1.0f : 1.0f;
    float th = ((float)K * ci) * si;
    float sn, cs; phase_sincos(th, &sn, &cs);
    return make_float2(cs, sgn * sn);
}

// ---------------- chain tail: level-24 factors + c2r pack ----------------
struct WPair { float2 wk, wmk; };

__device__ __forceinline__ WPair chain_tail(unsigned k, float Pr, float Pi,
                                            float c24, float s24) {
    const float sc = 1.0f / 33554432.0f;                  // 1/N
    unsigned mk = M24 - k;
    float thk = ((float)k  * c24) * s24;
    float thm = ((float)mk * c24) * s24;
    float snk, csk, snm, csm;
    phase_sincos(thk, &snk, &csk);
    phase_sincos(thm, &snm, &csm);

    float Skr = Pr * csk - Pi * snk;
    float Ski = Pr * snk + Pi * csk;
    float Smr = Pr * csm + Pi * snm;                      // conj(P) * e^{i*thm}
    float Smi = Pr * snm - Pi * csm;

    float Ar = Skr + Smr, Ai = Ski - Smi;
    float Br = Skr - Smr, Bi = Ski + Smi;
    float ts, tc;
    sincos_rev((float)k * (1.0f / 33554432.0f), &ts, &tc);
    float Cr = tc * Br - ts * Bi;
    float Ci = ts * Br + tc * Bi;

    WPair w;
    w.wk  = make_float2((Ar - Ci) * sc, (Ai + Cr) * sc);
    w.wmk = make_float2((Ar + Ci) * sc, (Cr - Ai) * sc);
    return w;
}

// ---------------- full chain (block-0 special rows only) ----------------
__device__ WPair chain_W_full(unsigned k, const float* __restrict__ el,
                              const float2* __restrict__ Q) {
    unsigned t = (unsigned)__builtin_ctz(k);              // t <= 23
    unsigned r = k & 0x3FFFFu;
    float Pr, Pi;
    if (r != 0u) {
        float2 q = Q[r];
        Pr = q.x; Pi = q.y;
    } else {
        // T_t = cos(fl32(fl32(2^t * c_t) * s_t)), t in [18,23]
        float ct = c_of((int)t);
        float st = s_of(el, (int)t);
        float p  = (float)(1u << t) * ct;
        float th = p * st;
        float sn, cs; phase_sincos(th, &sn, &cs);
        Pr = cs; Pi = 0.0f;
    }
#pragma unroll
    for (int i = 18; i <= 23; ++i) {
        unsigned hi = 1u << i;
        int sd = (int)((k + hi) & (2u * hi - 1u)) - (int)hi;
        int K  = (i <= (int)t) ? 0 : (sd < 0 ? -sd : sd);
        float sgn = (sd < 0) ? -1.0f : 1.0f;
        float th = ((float)K * c_of(i)) * s_of(el, i);
        float sn, cs; phase_sincos(th, &sn, &cs);
        float ssn = sgn * sn;
        float nr = Pr * cs - Pi * ssn;
        float ni = Pr * ssn + Pi * cs;
        Pr = nr; Pi = ni;
    }
    return chain_tail(k, Pr, Pi, c_of(24), s_of(el, 24));
}

// ---------------- row -> column map (32-row mirror-closed block sets) ----------------
__device__ __forceinline__ int c_of_row32(int b, int r) {
    if (b == 0) {
        if (r < 16)  return r;              // 0..15
        if (r == 16) return 32768;          // self-mirrored
        return 65536 - (r - 16);            // r=17..31 -> 65535..65521
    }
    return (r < 16) ? (16 * b + r) : (65536 - 16 * b - (r - 16));
}

// ---------------- Fused: build W (LDS) + radix-16^2 IDFT over k3 ----------------
// 512 threads, 32 columns/block (16 consecutive + 16 mirror-consecutive),
// 2048 blocks. LDS: flat 64 KiB with per-row rotation (no padding).
__global__ __launch_bounds__(512, 4) void fused_build_fft_a(const float* __restrict__ el,
                                                            const float2* __restrict__ Q,
                                                            float2* __restrict__ out) {
    __shared__ float2 lds2[8192];                         // exactly 64 KiB
#define LA(r, c_) lds2[(((r) << 8)) | ((((c_) + (r)) & 255))]
    int tid = threadIdx.x;
    int b  = xcd_swizzle(blockIdx.x, 2048);
    int pr = tid & 15;                                    // pair-row 0..15
    int kq = tid >> 4;                                    // 0..31

    if (b == 0 && pr == 0) {
        // c=0 (row 0) and c=32768 (row 16): full chains, both self-mirrored.
        int rsp = (kq < 16) ? 0 : 16;
        int kql = kq & 15;
        unsigned cb = (rsp == 0) ? 0u : 32768u;
#pragma unroll 1
        for (int u = 0; u < 8; ++u) {
            int k3 = kql + 16 * u;                        // 0..127
            if (rsp == 0 && k3 == 0) {
                float c24 = c_of(24), s24v = s_of(el, 24);
                float th = (16777216.0f * c24) * s24v;
                float sn, cs; phase_sincos(th, &sn, &cs);
                const float sc = 1.0f / 33554432.0f;
                LA(0, 0) = make_float2((1.0f + cs) * sc, (1.0f - cs) * sc);
                WPair w = chain_W_full(8388608u, el, Q);
                LA(0, 128) = w.wk;
            } else {
                unsigned k = cb + ((unsigned)k3 << 16);
                WPair w = chain_W_full(k, el, Q);
                if (rsp == 0) { LA(0, k3)  = w.wk; LA(0, 256 - k3)  = w.wmk; }
                else          { LA(16, k3) = w.wk; LA(16, 255 - k3) = w.wmk; }
            }
        }
    } else {
        int c = (b == 0) ? pr : (16 * b + pr);            // low-side column (>=1)
        float s18 = s_of(el, 18), s19 = s_of(el, 19), s20 = s_of(el, 20),
              s21 = s_of(el, 21), s22 = s_of(el, 22), s23 = s_of(el, 23),
              s24v = s_of(el, 24);
        // k = kbase + u*2^21, u=0..7 ; k3 = kq + 32u
        unsigned kbase = (unsigned)c + ((unsigned)kq << 16);
        unsigned rres  = kbase & 0x3FFFFu;                // nonzero
        float2 P1 = Q[rres];
        P1 = cmul(P1, cfac(18, kbase, c_of(18), s18));    // const across u
        P1 = cmul(P1, cfac(19, kbase, c_of(19), s19));    // const across u
        P1 = cmul(P1, cfac(20, kbase, c_of(20), s20));    // const across u
        float2 P2[2], P3[4];
#pragma unroll
        for (int j = 0; j < 2; ++j)
            P2[j] = cmul(P1, cfac(21, kbase + ((unsigned)j << 21), c_of(21), s21));
#pragma unroll
        for (int j = 0; j < 4; ++j)
            P3[j] = cmul(P2[j & 1], cfac(22, kbase + ((unsigned)j << 21), c_of(22), s22));

#pragma unroll 1
        for (int u = 0; u < 8; ++u) {
            int k3 = kq + 32 * u;
            unsigned k = kbase + ((unsigned)u << 21);
            float2 P = cmul(P3[u & 3], cfac(23, k, c_of(23), s23));
            WPair w = chain_tail(k, P.x, P.y, c_of(24), s24v);
            LA(pr, k3) = w.wk;
            LA(pr + 16, 255 - k3) = w.wmk;
        }
    }
    __syncthreads();

    // phase 1: thread (row, q) owns column-class q of row; row = tid&31, q = tid>>5
    int row = tid & 31;
    int q   = tid >> 5;                                   // 0..15
    float2 v[16];
#pragma unroll
    for (int n1 = 0; n1 < 16; ++n1) v[n1] = LA(row, q + 16 * n1);
    fft16_inv(v);
    ztwiddle(v, q);
#pragma unroll
    for (int K1 = 0; K1 < 16; ++K1) LA(row, K1 * 16 + q) = v[K1];  // own slot set
    __syncthreads();

    // phase 2: thread (row, q) owns K1=q; output t3 = q + 16*K2 (natural order)
#pragma unroll
    for (int n2 = 0; n2 < 16; ++n2) v[n2] = LA(row, q * 16 + n2);
    fft16_inv(v);
    int cr = c_of_row32(b, row);
#pragma unroll
    for (int K2 = 0; K2 < 16; ++K2)
        out[cr + ((q + 16 * K2) << 16)] = v[K2];
#undef LA
}

// ---------------- Stage B: twiddle + radix-16^2 IDFT over k2 (stride 256) ----------------
__global__ __launch_bounds__(256, 3) void fft_stage_b(const float2* __restrict__ in,
                                                      float2* __restrict__ out) {
    __shared__ float2 lds[16][257];
    int tid = threadIdx.x;
    int wg  = xcd_swizzle(blockIdx.x, 4096);
    int k1b = (wg & 15) * 16;
    int t3  = wg >> 4;
    int row = tid & 15;
    int q   = tid >> 4;                                   // n2 = q; loads ARE the phase-1 set

    float2 v[16];
    const float2* src = in + (k1b + row + (q << 8) + (t3 << 16));
#pragma unroll
    for (int u = 0; u < 16; ++u) v[u] = src[u << 12];     // k2 = q + 16u

    {   // inter-stage twiddle e^{+2pi i t3 k2 / 65536}
        float sb, cb; sincos_rev((float)(t3 * q)  * (1.0f / 65536.0f), &sb, &cb);
        float ssx, csx; sincos_rev((float)t3 * (1.0f / 4096.0f), &ssx, &csx);
        float2 w = make_float2(cb, sb), stp = make_float2(csx, ssx);
#pragma unroll
        for (int u = 0; u < 16; ++u) {
            v[u] = cmul(v[u], w);
            w = cmul(w, stp);
        }
    }
    fft16_inv(v);
    ztwiddle(v, q);
#pragma unroll
    for (int K1 = 0; K1 < 16; ++K1) lds[row][K1 * 16 + q] = v[K1];
    __syncthreads();

#pragma unroll
    for (int n2 = 0; n2 < 16; ++n2) v[n2] = lds[row][q * 16 + n2];
    fft16_inv(v);
#pragma unroll
    for (int K2 = 0; K2 < 16; ++K2)
        out[k1b + row + ((q + 16 * K2) << 8) + (t3 << 16)] = v[K2];
}

// ---------------- Stage C: twiddle + radix-16^2 IDFT over k1 (stride 1) ----------------
__global__ __launch_bounds__(256, 3) void fft_stage_c(const float2* __restrict__ in,
                                                      float2* __restrict__ out) {
    __shared__ float2 lds[16][257];
    int tid = threadIdx.x;
    int wg  = xcd_swizzle(blockIdx.x, 4096);
    int t3b = (wg & 15) * 16;
    int t2  = wg >> 4;

    {   // load one k1 column across 16 rows, twiddle, raw-stage to LDS
        int k1 = tid;
        const float2* src = in + (k1 + (t2 << 8) + (t3b << 16));
        float2 vb[16];
#pragma unroll
        for (int u = 0; u < 16; ++u) vb[u] = src[u << 16];
        int base = (t3b + (t2 << 8)) * k1;                // < 2^24, exact in float
        float sb, cb; sincos_rev((float)base * (1.0f / 16777216.0f), &sb, &cb);
        float ssx, csx; sincos_rev((float)k1 * (1.0f / 1048576.0f), &ssx, &csx);  // 16/2^24
        float2 w = make_float2(cb, sb), stp = make_float2(csx, ssx);
#pragma unroll
        for (int u = 0; u < 16; ++u) {
            lds[u][k1] = cmul(vb[u], w);
            w = cmul(w, stp);
        }
    }
    __syncthreads();

    int rr = tid & 15;
    int q  = tid >> 4;
    float2 v[16];
#pragma unroll
    for (int n1 = 0; n1 < 16; ++n1) v[n1] = lds[rr][q + 16 * n1];
    fft16_inv(v);
    ztwiddle(v, q);
#pragma unroll
    for (int K1 = 0; K1 < 16; ++K1) lds[rr][K1 * 16 + q] = v[K1];  // own slot set
    __syncthreads();

#pragma unroll
    for (int n2 = 0; n2 < 16; ++n2) v[n2] = lds[rr][q * 16 + n2];
    fft16_inv(v);
#pragma unroll
    for (int K2 = 0; K2 < 16; ++K2)
        out[(t3b + rr) + (t2 << 8) + ((q + 16 * K2) << 16)] = v[K2];
}

extern "C" void kernel_launch(void* const* d_in, const int* in_sizes, int n_in,
                              void* d_out, int out_size, void* d_ws, size_t ws_size,
                              hipStream_t stream) {
    const float* el = (const float*)d_in[0];   // 25 floats
    float2* Gd = (float2*)d_out;               // out buffer doubles as complex ping-pong
    float2* Q  = (float2*)d_ws;                // Q table (2 MiB) lives in ws until stage B

    // build_q (ws) -> fusedA: (chains+FFT) -> out -> stageB: out->ws (clobbers Q, ok)
    // -> stageC: ws->out (final real signal)
    hipLaunchKernelGGL(build_q,           dim3(1024), dim3(256), 0, stream, el, Q);
    hipLaunchKernelGGL(fused_build_fft_a, dim3(2048), dim3(512), 0, stream, el, Q, Gd);
    hipLaunchKernelGGL(fft_stage_b,       dim3(4096), dim3(256), 0, stream, Gd, (float2*)d_ws);
    hipLaunchKernelGGL(fft_stage_c,       dim3(4096), dim3(256), 0, stream, (float2*)d_ws, Gd);
}